// Round 1
// baseline (60.047 us; speedup 1.0000x reference)
//
#include <hip/hip_runtime.h>
#include <hip/hip_bf16.h>

// SingleDimHistLayer: soft histogram via fine-grid deposit + 145-tap convolution.
//
// Math: out[b,k] = (1/N) * sum_n [ g(u_n - k) - g(u_n - k - 1) ],  g(v)=sigmoid(2.5 v),
//       u = x*256.  Terms negligible outside |u - k - 0.5| <= 4.5 -> 145 fine taps
//       at 1/16 resolution.
// Deposit: nearest fine node (midpoint rule), 1 INTEGER LDS atomic per sample.
// This round: occupancy probe. 1024 threads/block (16 waves/CU vs 4 before),
// grid unchanged at 256 (1 block/CU), per-CU atomic work identical -> clean A/B
// on whether the deposit was DS-pipe-throughput-bound or latency/TLP-bound.
// Conv is split 4-ways per bin (tid>>2) + shfl reduce so conv wall time stays flat.

constexpr int KBINS   = 256;
constexpr int FSUB    = 16;                  // fine nodes per bin
constexpr int LPAD    = 64;                  // left halo (k=0 window reaches f=-64)
constexpr int TAPS    = 145;                 // window f in [16k-64, 16k+80]
// bank-skew addressing: addr = p + (p>>5); max logical p = 4224 -> 4356
constexpr int LDS_FH  = 4360;
constexpr int NPB     = 512 * 512;           // samples per batch
constexpr int BLK_PER_BATCH = 32;            // 8192 samples per block, grid = 256
constexpr int CHUNK   = NPB / BLK_PER_BATCH; // 8192
constexpr int THREADS = 1024;                // 16 waves/CU (was 256 -> 1 wave/SIMD)

__device__ __forceinline__ int skew(int p) { return p + (p >> 5); }

__global__ __launch_bounds__(THREADS)
void hist_kernel(const float* __restrict__ x, float* __restrict__ out) {
    __shared__ unsigned fh[LDS_FH];
    __shared__ float w[TAPS];
    const int tid = threadIdx.x;

    // zero fine hist
    for (int i = tid; i < LDS_FH; i += THREADS) fh[i] = 0u;

    // conv weights: w[j] = sigmoid(0.15625*(j-64)) - sigmoid(0.15625*(j-80))
    if (tid < TAPS) {
        float a = 0.15625f * (float)(tid - 64);
        float b = 0.15625f * (float)(tid - 80);
        w[tid] = 1.f / (1.f + __expf(-a)) - 1.f / (1.f + __expf(-b));
    }
    __syncthreads();

    const int b     = blockIdx.x / BLK_PER_BATCH;
    const int chunk = blockIdx.x % BLK_PER_BATCH;
    const float4* xv = (const float4*)(x + (size_t)b * NPB + (size_t)chunk * CHUNK);

    // deposit: 8192 samples/block, 2 float4 per thread, 1 int LDS atomic per sample.
    // addr = skew((int)(x*4096 + 64.5)) : LPAD and round-to-nearest folded into fmaf.
    #pragma unroll
    for (int it = 0; it < CHUNK / (4 * THREADS); ++it) {
        float4 v = xv[it * THREADS + tid];
        float vals[4] = {v.x, v.y, v.z, v.w};
        int addr[4];
        #pragma unroll
        for (int c = 0; c < 4; ++c) {
            float s = fmaf(vals[c], (float)(KBINS * FSUB), (float)LPAD + 0.5f);
            s = fminf(fmaxf(s, 0.f), 4224.f);            // defensive clamp (NaN -> 0)
            addr[c] = skew((int)s);
        }
        #pragma unroll
        for (int c = 0; c < 4; ++c)
            atomicAdd(&fh[addr[c]], 1u);
    }
    __syncthreads();

    // convolve: 4 threads per coarse bin, ~36 taps each, shfl pair-reduce.
    // bin k reads padded fine nodes [16k, 16k+144].
    {
        const int bin = tid >> 2;          // 0..255
        const int q   = tid & 3;
        const int j0  = q * 37;
        const int j1  = (j0 + 37 < TAPS) ? j0 + 37 : TAPS;
        const int base = bin * FSUB;
        float acc = 0.f;
        #pragma unroll 4
        for (int j = j0; j < j1; ++j)
            acc += w[j] * (float)fh[skew(base + j)];
        acc += __shfl_xor(acc, 1);
        acc += __shfl_xor(acc, 2);
        if (q == 0)
            unsafeAtomicAdd(&out[b * KBINS + bin], acc * (1.f / (float)NPB));
    }
}

extern "C" void kernel_launch(void* const* d_in, const int* in_sizes, int n_in,
                              void* d_out, int out_size, void* d_ws, size_t ws_size,
                              hipStream_t stream) {
    const float* x = (const float*)d_in[0];
    float* out = (float*)d_out;
    const int B = in_sizes[0] / NPB;   // 8

    hipMemsetAsync(d_out, 0, (size_t)out_size * sizeof(float), stream);
    hist_kernel<<<B * BLK_PER_BATCH, THREADS, 0, stream>>>(x, out);
}

// Round 2
// 59.764 us; speedup vs baseline: 1.0047x; 1.0047x over previous
//
#include <hip/hip_runtime.h>
#include <hip/hip_bf16.h>

// SingleDimHistLayer: soft histogram via fine-grid deposit + 145-tap convolution.
//
// Math: out[b,k] = (1/N) * sum_n [ g(u_n - k) - g(u_n - k - 1) ],  g(v)=sigmoid(2.5 v),
//       u = x*256.  Terms negligible outside |u - k - 0.5| <= 4.5 -> 145 fine taps
//       at 1/16 resolution.
// Deposit: nearest fine node (midpoint rule), 1 INTEGER LDS atomic per sample.
//
// Round 2: measurement-clarity round. The profile showed 256 MiB harness fills
// at ~40.6 us dominating top-5 and our kernel absent (<40.5 us) while dur_us=60.
// Remove ALL extraneous enqueued ops: no hipMemsetAsync, no global atomics.
// Blocks write per-chunk partials to d_ws (each slot written exactly once),
// a tiny reduce kernel sums 32 partials/batch. Our enqueued work is then
// provably hist(<40.5us) + reduce(~3us) -> dur_us tells us whether a harness
// fill sits inside the timed region (H1: dur stays ~60) or not (H2: dur ~52-57).

constexpr int KBINS   = 256;
constexpr int FSUB    = 16;                  // fine nodes per bin
constexpr int LPAD    = 64;                  // left halo (k=0 window reaches f=-64)
constexpr int TAPS    = 145;                 // window f in [16k-64, 16k+80]
// bank-skew addressing: addr = p + (p>>5); max logical p = 4224 -> 4356
constexpr int LDS_FH  = 4360;
constexpr int NPB     = 512 * 512;           // samples per batch
constexpr int BLK_PER_BATCH = 32;            // 8192 samples per block, grid = 256
constexpr int CHUNK   = NPB / BLK_PER_BATCH; // 8192
constexpr int THREADS = 1024;                // 16 waves/CU

__device__ __forceinline__ int skew(int p) { return p + (p >> 5); }

__global__ __launch_bounds__(THREADS)
void hist_kernel(const float* __restrict__ x, float* __restrict__ ws) {
    __shared__ unsigned fh[LDS_FH];
    __shared__ float w[TAPS];
    const int tid = threadIdx.x;

    // zero fine hist
    for (int i = tid; i < LDS_FH; i += THREADS) fh[i] = 0u;

    // conv weights: w[j] = sigmoid(0.15625*(j-64)) - sigmoid(0.15625*(j-80))
    if (tid < TAPS) {
        float a = 0.15625f * (float)(tid - 64);
        float b = 0.15625f * (float)(tid - 80);
        w[tid] = 1.f / (1.f + __expf(-a)) - 1.f / (1.f + __expf(-b));
    }
    __syncthreads();

    const int b     = blockIdx.x / BLK_PER_BATCH;
    const int chunk = blockIdx.x % BLK_PER_BATCH;
    const float4* xv = (const float4*)(x + (size_t)b * NPB + (size_t)chunk * CHUNK);

    // deposit: 8192 samples/block, 2 float4 per thread, 1 int LDS atomic per sample.
    // addr = skew((int)(x*4096 + 64.5)) : LPAD and round-to-nearest folded into fmaf.
    #pragma unroll
    for (int it = 0; it < CHUNK / (4 * THREADS); ++it) {
        float4 v = xv[it * THREADS + tid];
        float vals[4] = {v.x, v.y, v.z, v.w};
        int addr[4];
        #pragma unroll
        for (int c = 0; c < 4; ++c) {
            float s = fmaf(vals[c], (float)(KBINS * FSUB), (float)LPAD + 0.5f);
            s = fminf(fmaxf(s, 0.f), 4224.f);            // defensive clamp (NaN -> 0)
            addr[c] = skew((int)s);
        }
        #pragma unroll
        for (int c = 0; c < 4; ++c)
            atomicAdd(&fh[addr[c]], 1u);
    }
    __syncthreads();

    // convolve: 4 threads per coarse bin, ~36 taps each, shfl pair-reduce.
    // bin k reads padded fine nodes [16k, 16k+144].
    {
        const int bin = tid >> 2;          // 0..255
        const int q   = tid & 3;
        const int j0  = q * 37;
        const int j1  = (j0 + 37 < TAPS) ? j0 + 37 : TAPS;
        const int base = bin * FSUB;
        float acc = 0.f;
        #pragma unroll 4
        for (int j = j0; j < j1; ++j)
            acc += w[j] * (float)fh[skew(base + j)];
        acc += __shfl_xor(acc, 1);
        acc += __shfl_xor(acc, 2);
        // non-atomic partial write: each (block, bin) slot written exactly once
        if (q == 0)
            ws[(size_t)blockIdx.x * KBINS + bin] = acc;
    }
}

// reduce 32 per-chunk partials per batch -> out[b,k], apply 1/N
__global__ __launch_bounds__(KBINS)
void reduce_kernel(const float* __restrict__ ws, float* __restrict__ out) {
    const int b = blockIdx.x;
    const int k = threadIdx.x;
    const float* p = ws + (size_t)b * BLK_PER_BATCH * KBINS + k;
    float s = 0.f;
    #pragma unroll
    for (int c = 0; c < BLK_PER_BATCH; ++c)
        s += p[(size_t)c * KBINS];
    out[b * KBINS + k] = s * (1.f / (float)NPB);
}

extern "C" void kernel_launch(void* const* d_in, const int* in_sizes, int n_in,
                              void* d_out, int out_size, void* d_ws, size_t ws_size,
                              hipStream_t stream) {
    const float* x = (const float*)d_in[0];
    float* out = (float*)d_out;
    float* ws  = (float*)d_ws;     // needs B*32*256*4 = 256 KB; ws is far larger
    const int B = in_sizes[0] / NPB;   // 8

    hist_kernel<<<B * BLK_PER_BATCH, THREADS, 0, stream>>>(x, ws);
    reduce_kernel<<<B, KBINS, 0, stream>>>(ws, out);
}